// Round 9
// baseline (94106.201 us; speedup 1.0000x reference)
//
#include <hip/hip_runtime.h>

#define TT 4096
typedef unsigned int uint;
typedef unsigned long long u64;

#define TAGM 31u  // 5-bit wrap tag in mantissa LSBs (rel err 2^-19)

static __device__ __forceinline__ float sigm(float x) { return 1.f / (1.f + __expf(-x)); }
static __device__ __forceinline__ float ftanh(float x) {
  x = fminf(fmaxf(x, -15.f), 15.f);
  const float e = __expf(-2.f * x);
  return (1.f - e) / (1.f + e);
}
static __device__ __forceinline__ void lds_wave_fence() {
  asm volatile("s_waitcnt lgkmcnt(0)" ::: "memory");
  __builtin_amdgcn_sched_barrier(0);
}
static __device__ __forceinline__ uint tagw(float v, uint tg) {
  return (__float_as_uint(v) & ~TAGM) | tg;
}
// tag of step t: 1..31 for t>=0; 0 reserved for zero-initialized init state.
static __device__ __forceinline__ uint tg_of(int t) {
  return (t < 0) ? 0u : (uint)((((uint)t >> 3) % 31u) + 1u);
}
static __device__ __forceinline__ void posta(float* p, float v, uint tg) {
  __hip_atomic_store((uint*)p, tagw(v, tg), __ATOMIC_RELAXED, __HIP_MEMORY_SCOPE_AGENT);
}
static __device__ __forceinline__ u64 lda(const u64* q) {
  return __hip_atomic_load(q, __ATOMIC_RELAXED, __HIP_MEMORY_SCOPE_AGENT);
}
static __device__ __forceinline__ void stw(u64* q, u64 v) {  // plain (write-through) store
  __hip_atomic_store(q, v, __ATOMIC_RELAXED, __HIP_MEMORY_SCOPE_WORKGROUP);
}
static __device__ __forceinline__ u64 ld_sc0(const u64* q) {  // bypass L1, hit XCD-L2
  u64 r;
  asm volatile("global_load_dwordx2 %0, %1, off sc0\n\ts_waitcnt vmcnt(0)"
               : "=v"(r) : "v"(q) : "memory");
  return r;
}
static __device__ __forceinline__ bool tag2(u64 a, uint tg) {
  return ((((uint)a ^ tg) | ((uint)(a >> 32) ^ tg)) & TAGM) == 0u;
}
// MALL poll: spin on atom0 (sentinel), then fetch atoms 1,2 (cheap retries).
static __device__ __forceinline__ void poll_mall3(const u64* q, uint tg,
                                                  u64& a0, u64& a1, u64& a2) {
  a0 = lda(q);
  while (!tag2(a0, tg)) { __builtin_amdgcn_s_sleep(1); a0 = lda(q); }
  a1 = lda(q + 1);
  while (!tag2(a1, tg)) { __builtin_amdgcn_s_sleep(1); a1 = lda(q + 1); }
  a2 = lda(q + 2);
  while (!tag2(a2, tg)) { __builtin_amdgcn_s_sleep(1); a2 = lda(q + 2); }
}
// XCD-local poll (bounded): sc0 loads hit the shared XCD-L2 that the leader's
// plain stores wrote through. False if cap trips (wrong bid->XCD mapping).
static __device__ __forceinline__ bool poll_lbuf3(const u64* q, uint tg,
                                                  u64& a0, u64& a1, u64& a2) {
  int n = 0;
  a0 = ld_sc0(q);
  while (!tag2(a0, tg)) {
    if (++n > 1024) return false;
    __builtin_amdgcn_s_sleep(1);
    a0 = ld_sc0(q);
  }
  a1 = ld_sc0(q + 1);
  while (!tag2(a1, tg)) {
    if (++n > 1280) return false;
    __builtin_amdgcn_s_sleep(1);
    a1 = ld_sc0(q + 1);
  }
  a2 = ld_sc0(q + 2);
  while (!tag2(a2, tg)) {
    if (++n > 1536) return false;
    __builtin_amdgcn_s_sleep(1);
    a2 = ld_sc0(q + 2);
  }
  return true;
}
static __device__ __forceinline__ void unpack6(u64 a0, u64 a1, u64 a2, float* hp) {
  hp[0] = __uint_as_float((uint)a0 & ~TAGM);
  hp[1] = __uint_as_float((uint)(a0 >> 32) & ~TAGM);
  hp[2] = __uint_as_float((uint)a1 & ~TAGM);
  hp[3] = __uint_as_float((uint)(a1 >> 32) & ~TAGM);
  hp[4] = __uint_as_float((uint)a2 & ~TAGM);
  hp[5] = __uint_as_float((uint)(a2 >> 32) & ~TAGM);
}
// Hierarchical poll of one unit row; leader rebroadcasts, follower fast-path.
static __device__ __forceinline__ void poll_h(const u64* qm, u64* ql, uint tg,
                                              float* hp, bool leader, bool fast,
                                              int& mode) {
  u64 a0, a1, a2;
  if (!leader && fast && mode == 0) {
    if (poll_lbuf3(ql, tg, a0, a1, a2)) { unpack6(a0, a1, a2, hp); return; }
    mode = 1;  // sticky: this thread polls MALL directly from now on
  }
  poll_mall3(qm, tg, a0, a1, a2);
  if (leader) { stw(ql + 0, a0); stw(ql + 1, a1); stw(ql + 2, a2); }
  unpack6(a0, a1, a2, hp);
}
// acc[b] += v[b] * w over 6 batches; v is a 32B-aligned stride-8 row.
static __device__ __forceinline__ void fma6(const float* vp, float w, float acc[6]) {
  const float4 v0 = *(const float4*)vp;
  const float2 v1 = *(const float2*)(vp + 4);
  acc[0] += v0.x * w; acc[1] += v0.y * w; acc[2] += v0.z * w;
  acc[3] += v0.w * w; acc[4] += v1.x * w; acc[5] += v1.y * w;
}

// ================= K1: LSTM layer 1 — 32 WGs x 512 thr, 16 units/WG =========
__global__ __launch_bounds__(512, 2) void k_l1(
    const float* __restrict__ x, const float* __restrict__ Wi,
    const float* __restrict__ Wh, const float* __restrict__ bias,
    float* h1ring, float* lbuf1, float* h2ring, float* c1fin, float* seq1) {
  __shared__ float xl[2][128 * 8];
  __shared__ float hl[512 * 8];
  __shared__ float zred[2][8 * 520];
  __shared__ float bs[64];
  const int tid = threadIdx.x, slot = blockIdx.x;
  const int xcd = slot & 7;           // assumed XCD (round-robin heuristic)
  const bool leader = (slot < 8);     // one MALL-reader per assumed XCD
  const int c = tid & 63, w = tid >> 6;
  const int u0 = slot * 16;
  const int gcol = ((c >> 4) * 512) + u0 + (c & 15);
  float wh[64], wx[16];
#pragma unroll
  for (int kk = 0; kk < 64; ++kk) wh[kk] = Wh[(size_t)(w * 64 + kk) * 2048 + gcol];
#pragma unroll
  for (int kk = 0; kk < 16; ++kk) wx[kk] = Wi[(size_t)(w * 16 + kk) * 2048 + gcol];
  if (tid < 64) bs[tid] = bias[((tid >> 4) * 512) + u0 + (tid & 15)];
  const int gj = tid / 6, gb = tid % 6;  // gate lanes: tid<96
  float creg = 0.f;
  int mode = 0;
  {  // stage x[0] (transpose [b][k] -> [k][8-pad])
    const float v0 = x[tid];
    float v1 = 0.f;
    if (tid < 256) v1 = x[512 + tid];
    xl[0][(tid & 127) * 8 + (tid >> 7)] = v0;
    if (tid < 256) { const int i = 512 + tid; xl[0][(i & 127) * 8 + (i >> 7)] = v1; }
  }
  __syncthreads();

  for (int t = 0; t < TT; ++t) {
    const float* xn = x + (size_t)((t + 1 < TT) ? t + 1 : TT - 1) * 768;
    const float v0p = xn[tid];
    float v1p = 0.f;
    if (tid < 256) v1p = xn[512 + tid];
    float acc[6] = {0, 0, 0, 0, 0, 0};
    {
      const float* xb = xl[t & 1] + (size_t)(w * 16) * 8;
#pragma unroll
      for (int kk = 0; kk < 16; ++kk) fma6(xb + kk * 8, wx[kk], acc);
    }
    // poll h1[t-1] for unit tid (wave-self k-slice)
    {
      const u64* qm = (const u64*)(h1ring + (size_t)((t + 7) & 7) * 4096 + tid * 8);
      u64* ql = (u64*)(lbuf1 + (size_t)xcd * 16384 + (size_t)((t + 3) & 3) * 4096 + tid * 8);
      poll_h(qm, ql, tg_of(t - 1), hl + tid * 8, leader, true, mode);
    }
    lds_wave_fence();  // wave w wrote hl rows [64w,64w+64) == slice it reads
    {
      const float* hb = hl + (size_t)(w * 64) * 8;
#pragma unroll
      for (int kk = 0; kk < 64; ++kk) fma6(hb + kk * 8, wh[kk], acc);
    }
    {
      float* zr = zred[t & 1] + w * 520 + c * 8;
      *(float4*)zr = make_float4(acc[0], acc[1], acc[2], acc[3]);
      *(float2*)(zr + 4) = make_float2(acc[4], acc[5]);
    }
    {  // stage x[t+1]
      float* xs = xl[(t + 1) & 1];
      xs[(tid & 127) * 8 + (tid >> 7)] = v0p;
      if (tid < 256) { const int i = 512 + tid; xs[(i & 127) * 8 + (i >> 7)] = v1p; }
    }
    __syncthreads();  // the only barrier per step
    if (tid < 96) {
      __builtin_amdgcn_s_setprio(1);
      const float* zb = zred[t & 1];
      float z[4];
#pragma unroll
      for (int g = 0; g < 4; ++g) {
        const int cc = g * 16 + gj;
        float s = 0.f;
#pragma unroll
        for (int p = 0; p < 8; ++p) s += zb[p * 520 + cc * 8 + gb];
        z[g] = s + bs[cc];
      }
      creg = sigm(z[1]) * creg + sigm(z[0]) * ftanh(z[2]);
      const float hval = sigm(z[3]) * ftanh(creg);
      const int gu = u0 + gj;
      posta(h1ring + (size_t)(t & 7) * 4096 + gu * 8 + gb, hval, tg_of(t));
      __builtin_nontemporal_store(hval, seq1 + (size_t)t * 3072 + gu * 6 + gb);
      if (t == TT - 1) {  // serial handoff: plain stores, kernel-boundary flush
        *(uint*)(h2ring + (size_t)7 * 4096 + gu * 8 + gb) = tagw(hval, 0u);
        c1fin[gu * 6 + gb] = creg;
      }
      __builtin_amdgcn_s_setprio(0);
    }
  }
}

// ===== K2: runs AFTER k_l1 (stream order). 32 WGs; 16 L2-units + 4 L3-units
// each, L3 skewed one step behind L2. ========================================
__global__ __launch_bounds__(512, 2) void k_l23(
    const float* __restrict__ seq1, const float* __restrict__ Wi2,
    const float* __restrict__ Wh2, const float* __restrict__ b2,
    const float* __restrict__ Wi3, const float* __restrict__ Wh3,
    const float* __restrict__ b3, const float* __restrict__ c1fin,
    float* h2ring, float* lbuf2, float* h3ring, float* h3fin) {
  __shared__ float xls[2][512 * 8];
  __shared__ float hl[512 * 8];
  __shared__ float hl3[128 * 8];
  __shared__ float zred2[2][8 * 520];
  __shared__ float zred3[32 * 100];
  __shared__ float bs2[64];
  __shared__ float bs3[16];
  const int tid = threadIdx.x, slot = blockIdx.x;
  const int xcd = slot & 7;
  const bool leader = (slot < 8);
  const int c = tid & 63, w = tid >> 6;
  const int gj = tid / 6, gb = tid % 6;
  const int u0 = slot * 16;
  const int gcol = ((c >> 4) * 512) + u0 + (c & 15);
  float wh[64], wx[64];
#pragma unroll
  for (int kk = 0; kk < 64; ++kk) {
    wh[kk] = Wh2[(size_t)(w * 64 + kk) * 2048 + gcol];
    wx[kk] = Wi2[(size_t)(w * 64 + kk) * 2048 + gcol];
  }
  // L3: 16 cols (4 gates x 4 units), 32 k-slices of 20 over K=640 ([h2;h3])
  const int c3 = tid & 15, ks3 = tid >> 4;
  const int v0 = slot * 4;
  const int gcol3 = ((c3 >> 2) * 128) + v0 + (c3 & 3);
  float w3[20];
#pragma unroll
  for (int kk = 0; kk < 20; ++kk) {
    const int k = ks3 * 20 + kk;
    w3[kk] = (k < 512) ? Wi3[(size_t)k * 512 + gcol3]
                       : Wh3[(size_t)(k - 512) * 512 + gcol3];
  }
  if (tid < 64) bs2[tid] = b2[((tid >> 4) * 512) + u0 + (tid & 15)];
  if (tid < 16) bs3[tid] = b3[((tid >> 2) * 128) + v0 + (tid & 3)];
  float creg = (tid < 96) ? c1fin[(u0 + gj) * 6 + gb] : 0.f;
  float creg3 = 0.f;
  int mode = 0;
  {  // stage seq1[0] (packed [t][512][6])
    const float2 s0 = *(const float2*)(seq1 + (size_t)tid * 6);
    const float2 s1 = *(const float2*)(seq1 + (size_t)tid * 6 + 2);
    const float2 s2 = *(const float2*)(seq1 + (size_t)tid * 6 + 4);
    float* xs = xls[0] + tid * 8;
    *(float2*)xs = s0; *(float2*)(xs + 2) = s1; *(float2*)(xs + 4) = s2;
  }
  __syncthreads();

  for (int t = 0; t <= TT; ++t) {
    float2 q0 = make_float2(0, 0), q1 = q0, q2 = q0;
    float acc[6] = {0, 0, 0, 0, 0, 0};
    if (t < TT) {
      const int tn = (t + 1 < TT) ? t + 1 : TT - 1;  // prefetch seq1[t+1]
      const float* sp = seq1 + (size_t)tn * 3072 + (size_t)tid * 6;
      q0 = *(const float2*)(sp);
      q1 = *(const float2*)(sp + 2);
      q2 = *(const float2*)(sp + 4);
      const float* xb = xls[t & 1] + (size_t)(w * 64) * 8;
#pragma unroll
      for (int kk = 0; kk < 64; ++kk) fma6(xb + kk * 8, wx[kk], acc);
    }
    if (t >= 1 && tid < 128) {  // poll h3[t-2] (direct MALL; usually old)
      const u64* q3 = (const u64*)(h3ring + (size_t)((t + 6) & 7) * 1024 + tid * 8);
      u64 d0, d1, d2;
      poll_mall3(q3, tg_of(t - 2), d0, d1, d2);
      unpack6(d0, d1, d2, hl3 + tid * 8);
    }
    {  // poll h2[t-1] for unit tid (t=0 reads the k_l1 handoff: direct only)
      const u64* qm = (const u64*)(h2ring + (size_t)((t + 7) & 7) * 4096 + tid * 8);
      u64* ql = (u64*)(lbuf2 + (size_t)xcd * 16384 + (size_t)((t + 3) & 3) * 4096 + tid * 8);
      poll_h(qm, ql, tg_of(t - 1), hl + tid * 8, leader, t >= 1, mode);
    }
    lds_wave_fence();  // own-wave hl slice below; hl3 read only after B
    if (t < TT) {
      const float* hb = hl + (size_t)(w * 64) * 8;
#pragma unroll
      for (int kk = 0; kk < 64; ++kk) fma6(hb + kk * 8, wh[kk], acc);
      float* zr = zred2[t & 1] + w * 520 + c * 8;
      *(float4*)zr = make_float4(acc[0], acc[1], acc[2], acc[3]);
      *(float2*)(zr + 4) = make_float2(acc[4], acc[5]);
      float* xs = xls[(t + 1) & 1] + tid * 8;  // stage seq1[t+1]
      *(float2*)xs = q0; *(float2*)(xs + 2) = q1; *(float2*)(xs + 4) = q2;
    }
    __syncthreads();  // B
    if (t < TT && tid < 96) {  // L2 gates + post h2[t]
      __builtin_amdgcn_s_setprio(1);
      const float* zb = zred2[t & 1];
      float z[4];
#pragma unroll
      for (int g = 0; g < 4; ++g) {
        const int cc = g * 16 + gj;
        float s = 0.f;
#pragma unroll
        for (int p = 0; p < 8; ++p) s += zb[p * 520 + cc * 8 + gb];
        z[g] = s + bs2[cc];
      }
      creg = sigm(z[1]) * creg + sigm(z[0]) * ftanh(z[2]);
      const float hval = sigm(z[3]) * ftanh(creg);
      posta(h2ring + (size_t)(t & 7) * 4096 + (u0 + gj) * 8 + gb, hval, tg_of(t));
      __builtin_amdgcn_s_setprio(0);
    }
    if (t >= 1) {  // L3 FMA for step s=t-1 (hl=h2[t-1], hl3=h3[t-2])
      float a3[6] = {0, 0, 0, 0, 0, 0};
#pragma unroll
      for (int kk = 0; kk < 20; ++kk) {
        const int k = ks3 * 20 + kk;
        const float* vp = (k < 512) ? (hl + (size_t)k * 8) : (hl3 + (size_t)(k - 512) * 8);
        fma6(vp, w3[kk], a3);
      }
      float* zr = zred3 + ks3 * 100 + c3 * 6;
      *(float2*)(zr) = make_float2(a3[0], a3[1]);
      *(float2*)(zr + 2) = make_float2(a3[2], a3[3]);
      *(float2*)(zr + 4) = make_float2(a3[4], a3[5]);
    }
    __syncthreads();  // C
    if (t >= 1 && tid < 24) {  // L3 gates + post h3[t-1]
      __builtin_amdgcn_s_setprio(1);
      const int s = t - 1;
      const int j3 = tid / 6;
      float z3[4];
#pragma unroll
      for (int g = 0; g < 4; ++g) {
        const int cc3 = g * 4 + j3;
        float sum = 0.f;
#pragma unroll
        for (int r = 0; r < 32; ++r) sum += zred3[r * 100 + cc3 * 6 + gb];
        z3[g] = sum + bs3[cc3];
      }
      creg3 = sigm(z3[1]) * creg3 + sigm(z3[0]) * ftanh(z3[2]);
      const float hv3 = sigm(z3[3]) * ftanh(creg3);
      posta(h3ring + (size_t)(s & 7) * 1024 + (v0 + j3) * 8 + gb, hv3, tg_of(s));
      if (s == TT - 1) h3fin[(v0 + j3) * 6 + gb] = hv3;
      __builtin_amdgcn_s_setprio(0);
    }
  }
}

// ================= K3: out[b] = h3fin[:,b] @ Wl + bl ========================
__global__ void k_out(const float* __restrict__ h3fin, const float* __restrict__ Wl,
                      const float* __restrict__ bl, float* __restrict__ out) {
  const int tid = threadIdx.x;  // 64
  float p[6] = {0, 0, 0, 0, 0, 0};
  for (int k = tid; k < 128; k += 64) {
    const float w = Wl[k];
#pragma unroll
    for (int b = 0; b < 6; ++b) p[b] += h3fin[k * 6 + b] * w;
  }
#pragma unroll
  for (int off = 32; off > 0; off >>= 1) {
#pragma unroll
    for (int b = 0; b < 6; ++b) p[b] += __shfl_down(p[b], off);
  }
  if (tid == 0) {
#pragma unroll
    for (int b = 0; b < 6; ++b) out[b] = p[b] + bl[0];
  }
}

// ================= host launcher ============================================
extern "C" void kernel_launch(void* const* d_in, const int* in_sizes, int n_in,
                              void* d_out, int out_size, void* d_ws, size_t ws_size,
                              hipStream_t stream) {
  (void)in_sizes; (void)n_in; (void)out_size;
  const float* x   = (const float*)d_in[0];
  const float* Wi1 = (const float*)d_in[1];
  const float* Wh1 = (const float*)d_in[2];
  const float* b1  = (const float*)d_in[3];
  const float* Wi2 = (const float*)d_in[4];
  const float* Wh2 = (const float*)d_in[5];
  const float* b2  = (const float*)d_in[6];
  const float* Wi3 = (const float*)d_in[7];
  const float* Wh3 = (const float*)d_in[8];
  const float* b3  = (const float*)d_in[9];
  const float* Wl  = (const float*)d_in[10];
  const float* bl  = (const float*)d_in[11];

  // ws layout (bytes):
  //   [0)        h1ring  8 slots x 512 u x 8f        = 131072
  //   [131072)   h2ring                              = 131072
  //   [262144)   h3ring  8 x 128 x 8f                =  32768
  //   [294912)   lbuf1   8 xcd x 4 slots x 512 x 8f  = 524288
  //   [819200)   lbuf2                               = 524288
  //   [1343488)  c1fin   3072f                       =  12288
  //   [1355776)  h3fin   768f                        =   3072 (pad to 1359872)
  //   [1359872)  seq1    4096 x 512 x 6 f            = 50331648
  char* wsb = (char*)d_ws;
  float* h1ring = (float*)(wsb + 0);
  float* h2ring = (float*)(wsb + 131072);
  float* h3ring = (float*)(wsb + 262144);
  float* lbuf1  = (float*)(wsb + 294912);
  float* lbuf2  = (float*)(wsb + 819200);
  float* c1fin  = (float*)(wsb + 1343488);
  float* h3fin  = (float*)(wsb + 1355776);
  float* seq1   = (float*)(wsb + 1359872);

  const size_t need = 1359872 + (size_t)TT * 512 * 6 * sizeof(float);
  if (ws_size < need) {
    hipMemsetAsync(d_out, 0, 6 * sizeof(float), stream);
    return;
  }

  // zero rings/lbufs/state each call. Zeroed = tag 0 = valid init (h[-1]=0);
  // steady-state tags are 1..31, so zeros can never false-match mid-run.
  hipMemsetAsync(d_ws, 0, 1359872, stream);

  // Phases are inherently serial (L2 init = L1 final state): stream order is
  // the dependency; no cross-kernel polling exists.
  k_l1 <<<32, 512, 0, stream>>>(x, Wi1, Wh1, b1, h1ring, lbuf1, h2ring, c1fin, seq1);
  k_l23<<<32, 512, 0, stream>>>(seq1, Wi2, Wh2, b2, Wi3, Wh3, b3, c1fin,
                                h2ring, lbuf2, h3ring, h3fin);
  k_out<<<1, 64, 0, stream>>>(h3fin, Wl, bl, (float*)d_out);
}